// Round 6
// baseline (275.091 us; speedup 1.0000x reference)
//
#include <hip/hip_runtime.h>
#include <hip/hip_bf16.h>

// Fused MHA block. B=4, S=2048, D=768, H=16, DH=48, causal, LayerNorm(eps=1e-3).
// FP32 harness buffers; bf16 MFMA internally (threshold is bf16-lenient, 2% rel).
//
// Pipeline:
//   1. transpose_w : Wt[n][k] = bf16(W[k][n])
//   2. qkv_proj    : MFMA GEMM (128x128, BK=32), XCD-swizzled, fully software-
//                    pipelined: reg-prefetch distance 2 (global), LDS double
//                    buffer, ONE barrier per k-step. Q prescaled.
//   3. attn        : MFMA flash attn, operand-swapped S^T = (K-frag)x(Q-frag),
//                    packed b64 P writes, lane-local l partials, double-buffered
//                    K/V, 1 barrier/step.
//   4. lnorm       : vectorized LayerNorm, fp32 out.

#define DMODEL 768
#define NHEAD  16
#define DHEAD  48
#define SEQ    2048
#define NBATCH 4
#define NROWS  (NBATCH * SEQ)                 // 8192
// Q prescale: 1/sqrt(48) * log2(e)  -> softmax = single v_exp_f32 (2^x)
#define QSCALE (0.14433756729740643f * 1.4426950408889634f)

typedef __bf16 bf16x8 __attribute__((ext_vector_type(8)));
typedef float  f32x4  __attribute__((ext_vector_type(4)));

// ---------------- 1. transpose + cvt weights ----------------
__global__ __launch_bounds__(256) void transpose_w(
    const float* __restrict__ Wq,
    const float* __restrict__ Wk,
    const float* __restrict__ Wv,
    __hip_bfloat16* __restrict__ Wt)
{
    __shared__ __hip_bfloat16 tile[32][33];
    int bid = blockIdx.x;
    int mat = bid / 576;
    int t   = bid - mat * 576;
    int tr  = t / 24, tc = t - (t / 24) * 24;
    const float* W = (mat == 0) ? Wq : (mat == 1) ? Wk : Wv;
    __hip_bfloat16* O = Wt + (size_t)mat * DMODEL * DMODEL;
    int tx = threadIdx.x & 31, ty = threadIdx.x >> 5;
#pragma unroll
    for (int i = 0; i < 32; i += 8)
        tile[ty + i][tx] = __float2bfloat16(W[(size_t)(tr * 32 + ty + i) * DMODEL + tc * 32 + tx]);
    __syncthreads();
#pragma unroll
    for (int i = 0; i < 32; i += 8)
        O[(size_t)(tc * 32 + ty + i) * DMODEL + tr * 32 + tx] = tile[tx][ty + i];
}

// ---------------- 2. QKV projection: pipelined MFMA GEMM, XCD-swizzled ----------
// 128x128 tile, BK=32, 4 waves 2x2. Reg prefetch dist 2, LDS dbuf, 1 barrier/step.
__global__ __launch_bounds__(256) void qkv_proj(
    const float* __restrict__ xq,
    const float* __restrict__ xk,
    const float* __restrict__ xv,
    const __hip_bfloat16* __restrict__ Wt,
    const float* __restrict__ bq,
    const float* __restrict__ bk,
    const float* __restrict__ bv,
    __hip_bfloat16* __restrict__ Qr,
    __hip_bfloat16* __restrict__ Kr,
    __hip_bfloat16* __restrict__ Vt)
{
    __shared__ __hip_bfloat16 As[2][128 * 32];
    __shared__ __hip_bfloat16 Bs[2][128 * 32];

    // XCD swizzle: all 6 nt-blocks of one (mat,mt) share bid%8 -> same XCD L2.
    int xcd  = blockIdx.x & 7;
    int s    = blockIdx.x >> 3;
    int nt   = s % 6;
    int pair = (s / 6) * 8 + xcd;
    int mat  = pair >> 6;
    int mt   = pair & 63;
    int m0   = mt * 128, n0 = nt * 128;

    const float* X          = (mat == 0) ? xq : (mat == 1) ? xk : xv;
    const __hip_bfloat16* W = Wt + (size_t)mat * DMODEL * DMODEL;
    const float* bias       = (mat == 0) ? bq : (mat == 1) ? bk : bv;

    int tid  = threadIdx.x;
    int w    = tid >> 6, lane = tid & 63;
    int l16  = lane & 15, quad = lane >> 4;
    int wm   = w >> 1, wn = w & 1;

    // staging map: thread -> (row rS, cols cS..cS+15) of the 128x32 tile
    int rS = tid >> 1;                 // 0..127
    int cS = (tid & 1) << 4;           // 0 or 16
    const float*          xb = X + (size_t)(m0 + rS) * DMODEL + cS;
    const __hip_bfloat16* wb = W + (size_t)(n0 + rS) * DMODEL + cS;
    int ldsOff = rS * 32 + cS;

    float4 fA0, fA1, fA2, fA3;         // prefetched A (fp32, 16 elems)
    uint4  rB0, rB1;                   // prefetched B (bf16, 16 elems)

#define QKV_LOAD(k0_) {                                                        \
        fA0 = *(const float4*)(xb + (k0_));                                    \
        fA1 = *(const float4*)(xb + (k0_) + 4);                                \
        fA2 = *(const float4*)(xb + (k0_) + 8);                                \
        fA3 = *(const float4*)(xb + (k0_) + 12);                               \
        rB0 = *(const uint4*)(wb + (k0_));                                     \
        rB1 = *(const uint4*)(wb + (k0_) + 8); }

#define QKV_STORE(buf_) {                                                      \
        *(bf16x8*)&As[buf_][ldsOff] =                                          \
            (bf16x8){ (__bf16)fA0.x, (__bf16)fA0.y, (__bf16)fA0.z, (__bf16)fA0.w, \
                      (__bf16)fA1.x, (__bf16)fA1.y, (__bf16)fA1.z, (__bf16)fA1.w }; \
        *(bf16x8*)&As[buf_][ldsOff + 8] =                                      \
            (bf16x8){ (__bf16)fA2.x, (__bf16)fA2.y, (__bf16)fA2.z, (__bf16)fA2.w, \
                      (__bf16)fA3.x, (__bf16)fA3.y, (__bf16)fA3.z, (__bf16)fA3.w }; \
        *(uint4*)&Bs[buf_][ldsOff]     = rB0;                                  \
        *(uint4*)&Bs[buf_][ldsOff + 8] = rB1; }

    f32x4 acc[4][4] = {};

    QKV_LOAD(0);
    QKV_STORE(0);
    QKV_LOAD(32);
    __syncthreads();

    for (int it = 0; it < 24; ++it) {
        int buf = it & 1;
        if (it + 1 < 24) QKV_STORE(buf ^ 1);          // tile it+1 (regs) -> other buffer
        if (it + 2 < 24) QKV_LOAD((it + 2) * 32);     // global prefetch, 2 steps ahead

        bf16x8 a[4], b[4];
#pragma unroll
        for (int i = 0; i < 4; ++i)
            a[i] = *(const bf16x8*)&As[buf][(wm * 64 + i * 16 + l16) * 32 + quad * 8];
#pragma unroll
        for (int j = 0; j < 4; ++j)
            b[j] = *(const bf16x8*)&Bs[buf][(wn * 64 + j * 16 + l16) * 32 + quad * 8];
#pragma unroll
        for (int i = 0; i < 4; ++i)
#pragma unroll
            for (int j = 0; j < 4; ++j)
                acc[i][j] = __builtin_amdgcn_mfma_f32_16x16x32_bf16(a[i], b[j], acc[i][j], 0, 0, 0);

        __syncthreads();
    }
#undef QKV_LOAD
#undef QKV_STORE

    // epilogue
#pragma unroll
    for (int j = 0; j < 4; ++j) {
        int col = n0 + wn * 64 + j * 16 + l16;
        float bc = bias[col];
        if (mat == 0) {
#pragma unroll
            for (int i = 0; i < 4; ++i) {
                int row0 = m0 + wm * 64 + i * 16 + quad * 4;
#pragma unroll
                for (int r = 0; r < 4; ++r)
                    Qr[(size_t)(row0 + r) * DMODEL + col] =
                        __float2bfloat16((acc[i][j][r] + bc) * QSCALE);
            }
        } else if (mat == 1) {
#pragma unroll
            for (int i = 0; i < 4; ++i) {
                int row0 = m0 + wm * 64 + i * 16 + quad * 4;
#pragma unroll
                for (int r = 0; r < 4; ++r)
                    Kr[(size_t)(row0 + r) * DMODEL + col] =
                        __float2bfloat16(acc[i][j][r] + bc);
            }
        } else {
            int h = col / 48, dh = col - h * 48;
#pragma unroll
            for (int i = 0; i < 4; ++i) {
                int row0 = m0 + wm * 64 + i * 16 + quad * 4;
                int bb = row0 >> 11, s0 = row0 & 2047;
                ushort4 pk;
                union { __hip_bfloat16 b; unsigned short u; } cv;
                cv.b = __float2bfloat16(acc[i][j][0] + bc); pk.x = cv.u;
                cv.b = __float2bfloat16(acc[i][j][1] + bc); pk.y = cv.u;
                cv.b = __float2bfloat16(acc[i][j][2] + bc); pk.z = cv.u;
                cv.b = __float2bfloat16(acc[i][j][3] + bc); pk.w = cv.u;
                *(ushort4*)(Vt + ((size_t)(bb * NHEAD + h) * DHEAD + dh) * SEQ + s0) = pk;
            }
        }
    }
}

// ---------------- 3. MFMA causal flash attention, operand-swapped ----------------
__global__ __launch_bounds__(256) void attn(
    const __hip_bfloat16* __restrict__ Qr,
    const __hip_bfloat16* __restrict__ Kr,
    const __hip_bfloat16* __restrict__ Vt,
    __hip_bfloat16* __restrict__ Ao)
{
    __shared__ __hip_bfloat16 Ks[2][64][72];   // cols 48..63 zeroed (DH pad)
    __shared__ __hip_bfloat16 Vs[2][48][72];   // V^T tile [d][kk]
    __shared__ __hip_bfloat16 Ps[4][32][72];   // per-wave P, [q_local][k], A-frag layout

    int tid  = threadIdx.x;
    int w    = tid >> 6, lane = tid & 63;
    int l16  = lane & 15, quad = lane >> 4;
    int bh   = blockIdx.x & 63;
    int qt   = 15 - (blockIdx.x >> 6);         // heavy q-tiles dispatch first
    int q0   = qt * 128;
    int b    = bh >> 4, h = bh & 15;
    size_t rowbase = (size_t)b * SEQ;

    const __hip_bfloat16* Qp = Qr + rowbase * DMODEL + h * DHEAD;
    const __hip_bfloat16* Kp = Kr + rowbase * DMODEL + h * DHEAD;
    const __hip_bfloat16* Vp = Vt + (size_t)bh * DHEAD * SEQ;

    for (int idx = tid; idx < 1024; idx += 256) {
        int buf = idx >> 9, r = (idx >> 3) & 63, c = idx & 7;
        ((unsigned int*)&Ks[buf][r][48])[c] = 0u;
    }

    bf16x8 bQ0[2], bQ1[2];
#pragma unroll
    for (int i = 0; i < 2; ++i) {
        int qrow = q0 + w * 32 + i * 16 + l16;
        bQ0[i] = *(const bf16x8*)(Qp + (size_t)qrow * DMODEL + quad * 8);
        bQ1[i] = (bf16x8){};
        if (quad < 2)
            bQ1[i] = *(const bf16x8*)(Qp + (size_t)qrow * DMODEL + 32 + quad * 8);
    }

    int rK = tid >> 2, oK = (tid & 3) * 12;
    int dV = tid >> 3, oV = (tid & 7) * 8;

    uint2 kr0, kr1, kr2; uint4 vr0, vr1;

#define ATTN_LOAD(kt_) {                                                        \
        int k0_ = (kt_) * 64;                                                   \
        const __hip_bfloat16* kb_ = Kp + (size_t)(k0_ + rK) * DMODEL + oK;      \
        kr0 = *(const uint2*)(kb_);                                             \
        kr1 = *(const uint2*)(kb_ + 4);                                         \
        kr2 = *(const uint2*)(kb_ + 8);                                         \
        vr0 = *(const uint4*)(Vp + (size_t)dV * SEQ + k0_ + oV);                \
        if (tid < 128) vr1 = *(const uint4*)(Vp + (size_t)(32 + dV) * SEQ + k0_ + oV); }

#define ATTN_STORE(buf_) {                                                      \
        __hip_bfloat16* kd_ = &Ks[buf_][rK][oK];                                \
        *(uint2*)(kd_)     = kr0;                                               \
        *(uint2*)(kd_ + 4) = kr1;                                               \
        *(uint2*)(kd_ + 8) = kr2;                                               \
        *(uint4*)&Vs[buf_][dV][oV] = vr0;                                       \
        if (tid < 128) *(uint4*)&Vs[buf_][32 + dV][oV] = vr1; }

    f32x4 O[2][3] = {};
    float lsum[2] = {0.f, 0.f};

    int ktmax = 2 * qt + 1;
    ATTN_LOAD(0);
    ATTN_STORE(0);
    if (ktmax >= 1) ATTN_LOAD(1);
    __syncthreads();

    for (int kt = 0; kt <= ktmax; ++kt) {
        int buf = kt & 1;
        int k0  = kt * 64;
        if (kt + 1 <= ktmax) ATTN_STORE(buf ^ 1);
        if (kt + 2 <= ktmax) ATTN_LOAD(kt + 2);

        bf16x8 aK0[4], aK1[4];
#pragma unroll
        for (int t = 0; t < 4; ++t) {
            aK0[t] = *(const bf16x8*)&Ks[buf][16 * t + l16][quad * 8];
            aK1[t] = *(const bf16x8*)&Ks[buf][16 * t + l16][32 + quad * 8];
        }

#pragma unroll
        for (int i = 0; i < 2; ++i) {
            int qbase = q0 + w * 32 + i * 16;
            if (k0 > qbase + 15) continue;

            f32x4 s[4];
#pragma unroll
            for (int t = 0; t < 4; ++t) {
                f32x4 z = {};
                z    = __builtin_amdgcn_mfma_f32_16x16x32_bf16(aK0[t], bQ0[i], z, 0, 0, 0);
                s[t] = __builtin_amdgcn_mfma_f32_16x16x32_bf16(aK1[t], bQ1[i], z, 0, 0, 0);
            }

            if (k0 + 63 > qbase) {
                int qg = qbase + l16;
#pragma unroll
                for (int t = 0; t < 4; ++t) {
                    int kg = k0 + 16 * t + quad * 4;
#pragma unroll
                    for (int r = 0; r < 4; ++r)
                        if (kg + r > qg) s[t][r] = -1e30f;
                }
            }

            float ls = 0.f;
#pragma unroll
            for (int t = 0; t < 4; ++t) {
                float p0 = exp2f(s[t][0]), p1 = exp2f(s[t][1]);
                float p2 = exp2f(s[t][2]), p3 = exp2f(s[t][3]);
                ls += (p0 + p1) + (p2 + p3);
                union { __bf16 hv[4]; uint2 u2; } pk;
                pk.hv[0] = (__bf16)p0; pk.hv[1] = (__bf16)p1;
                pk.hv[2] = (__bf16)p2; pk.hv[3] = (__bf16)p3;
                *(uint2*)&Ps[w][i * 16 + l16][16 * t + quad * 4] = pk.u2;
            }
            lsum[i] += ls;
        }

        bf16x8 bV0[3], bV1[3];
#pragma unroll
        for (int dt = 0; dt < 3; ++dt) {
            bV0[dt] = *(const bf16x8*)&Vs[buf][dt * 16 + l16][quad * 8];
            bV1[dt] = *(const bf16x8*)&Vs[buf][dt * 16 + l16][32 + quad * 8];
        }

#pragma unroll
        for (int i = 0; i < 2; ++i) {
            int qbase = q0 + w * 32 + i * 16;
            if (k0 > qbase + 15) continue;
            bf16x8 aP0 = *(const bf16x8*)&Ps[w][i * 16 + l16][quad * 8];
            bf16x8 aP1 = *(const bf16x8*)&Ps[w][i * 16 + l16][32 + quad * 8];
#pragma unroll
            for (int dt = 0; dt < 3; ++dt) {
                O[i][dt] = __builtin_amdgcn_mfma_f32_16x16x32_bf16(aP0, bV0[dt], O[i][dt], 0, 0, 0);
                O[i][dt] = __builtin_amdgcn_mfma_f32_16x16x32_bf16(aP1, bV1[dt], O[i][dt], 0, 0, 0);
            }
        }

        __syncthreads();
    }

#pragma unroll
    for (int i = 0; i < 2; ++i) {
        lsum[i] += __shfl_xor(lsum[i], 16, 64);
        lsum[i] += __shfl_xor(lsum[i], 32, 64);
    }

#pragma unroll
    for (int i = 0; i < 2; ++i) {
#pragma unroll
        for (int r = 0; r < 4; ++r) {
            float linv = 1.f / __shfl(lsum[i], quad * 4 + r, 64);
            size_t g = (rowbase + q0 + w * 32 + i * 16 + quad * 4 + r) * DMODEL + h * DHEAD + l16;
            Ao[g + 0]  = __float2bfloat16(O[i][0][r] * linv);
            Ao[g + 16] = __float2bfloat16(O[i][1][r] * linv);
            Ao[g + 32] = __float2bfloat16(O[i][2][r] * linv);
        }
    }
#undef ATTN_LOAD
#undef ATTN_STORE
}

// ---------------- 4. LayerNorm (eps = 1e-3), vectorized, fp32 out ----------------
__global__ __launch_bounds__(192) void lnorm(
    const __hip_bfloat16* __restrict__ Ao,
    const float* __restrict__ gamma,
    const float* __restrict__ beta,
    float* __restrict__ out)
{
    __shared__ float rs_[3], rq_[3];
    int row = blockIdx.x;
    int t   = threadIdx.x;
    size_t base = (size_t)row * DMODEL + t * 4;

    ushort4 u = *(const ushort4*)(Ao + base);
    float x0, x1, x2, x3;
    { unsigned int v = (unsigned int)u.x << 16; __builtin_memcpy(&x0, &v, 4); }
    { unsigned int v = (unsigned int)u.y << 16; __builtin_memcpy(&x1, &v, 4); }
    { unsigned int v = (unsigned int)u.z << 16; __builtin_memcpy(&x2, &v, 4); }
    { unsigned int v = (unsigned int)u.w << 16; __builtin_memcpy(&x3, &v, 4); }

    float s = x0 + x1 + x2 + x3;
    float q = x0 * x0 + x1 * x1 + x2 * x2 + x3 * x3;
#pragma unroll
    for (int m = 32; m >= 1; m >>= 1) {
        s += __shfl_xor(s, m, 64);
        q += __shfl_xor(q, m, 64);
    }
    int wv = t >> 6;
    if ((t & 63) == 0) { rs_[wv] = s; rq_[wv] = q; }
    __syncthreads();
    float ts = rs_[0] + rs_[1] + rs_[2];
    float tq = rq_[0] + rq_[1] + rq_[2];
    float mu  = ts * (1.f / 768.f);
    float var = tq * (1.f / 768.f) - mu * mu;
    float rstd = rsqrtf(var + 1e-3f);

    float4 g  = *(const float4*)(gamma + t * 4);
    float4 be = *(const float4*)(beta + t * 4);
    float4 o;
    o.x = (x0 - mu) * rstd * g.x + be.x;
    o.y = (x1 - mu) * rstd * g.y + be.y;
    o.z = (x2 - mu) * rstd * g.z + be.z;
    o.w = (x3 - mu) * rstd * g.w + be.w;
    *(float4*)(out + base) = o;
}

extern "C" void kernel_launch(void* const* d_in, const int* in_sizes, int n_in,
                              void* d_out, int out_size, void* d_ws, size_t ws_size,
                              hipStream_t stream) {
    const float* q     = (const float*)d_in[0];
    const float* k     = (const float*)d_in[1];
    const float* v     = (const float*)d_in[2];
    const float* Wq    = (const float*)d_in[3];
    const float* bq    = (const float*)d_in[4];
    const float* Wk    = (const float*)d_in[5];
    const float* bk    = (const float*)d_in[6];
    const float* Wv    = (const float*)d_in[7];
    const float* bv    = (const float*)d_in[8];
    const float* gamma = (const float*)d_in[9];
    const float* beta  = (const float*)d_in[10];

    char* basep = (char*)d_ws;
    __hip_bfloat16* Wt = (__hip_bfloat16*)basep;
    __hip_bfloat16* Qr = (__hip_bfloat16*)(basep + 3538944);
    __hip_bfloat16* Kr = Qr + (size_t)NROWS * DMODEL;
    __hip_bfloat16* Vt = Kr + (size_t)NROWS * DMODEL;
    __hip_bfloat16* Ao = Vt + (size_t)NROWS * DMODEL;
    float* out = (float*)d_out;

    hipLaunchKernelGGL(transpose_w, dim3(1728), dim3(256), 0, stream, Wq, Wk, Wv, Wt);
    hipLaunchKernelGGL(qkv_proj, dim3(1152), dim3(256), 0, stream,
                       q, k, v, Wt, bq, bk, bv, Qr, Kr, Vt);
    hipLaunchKernelGGL(attn, dim3(1024), dim3(256), 0, stream, Qr, Kr, Vt, Ao);
    hipLaunchKernelGGL(lnorm, dim3(8192), dim3(192), 0, stream, Ao, gamma, beta, out);
}

// Round 7
// 265.384 us; speedup vs baseline: 1.0366x; 1.0366x over previous
//
#include <hip/hip_runtime.h>
#include <hip/hip_bf16.h>

// Fused MHA block. B=4, S=2048, D=768, H=16, DH=48, causal, LayerNorm(eps=1e-3).
// FP32 harness buffers; bf16 MFMA internally (threshold is bf16-lenient, 2% rel).
//
// Pipeline:
//   1. transpose_w : Wt[n][k] = bf16(W[k][n])
//   2. qkv_proj    : MFMA GEMM (128x128, BK=32), XCD-swizzled, software-pipelined
//                    (reg prefetch dist 2, LDS dbuf, 1 barrier/step).
//                    __launch_bounds__(256,2): VGPR cap ~256 so the prefetch
//                    registers stay live (VGPR=80 default collapsed the pipeline).
//   3. attn        : MFMA flash attn, operand-swapped S^T = (K-frag)x(Q-frag),
//                    packed b64 P writes, lane-local l partials, double-buffered
//                    K/V, 1 barrier/step. __launch_bounds__(256,3) to match the
//                    LDS-imposed 3 blocks/CU while freeing register headroom.
//   4. lnorm       : vectorized LayerNorm, fp32 out.

#define DMODEL 768
#define NHEAD  16
#define DHEAD  48
#define SEQ    2048
#define NBATCH 4
#define NROWS  (NBATCH * SEQ)                 // 8192
// Q prescale: 1/sqrt(48) * log2(e)  -> softmax = single v_exp_f32 (2^x)
#define QSCALE (0.14433756729740643f * 1.4426950408889634f)

typedef __bf16 bf16x8 __attribute__((ext_vector_type(8)));
typedef float  f32x4  __attribute__((ext_vector_type(4)));

// ---------------- 1. transpose + cvt weights ----------------
__global__ __launch_bounds__(256) void transpose_w(
    const float* __restrict__ Wq,
    const float* __restrict__ Wk,
    const float* __restrict__ Wv,
    __hip_bfloat16* __restrict__ Wt)
{
    __shared__ __hip_bfloat16 tile[32][33];
    int bid = blockIdx.x;
    int mat = bid / 576;
    int t   = bid - mat * 576;
    int tr  = t / 24, tc = t - (t / 24) * 24;
    const float* W = (mat == 0) ? Wq : (mat == 1) ? Wk : Wv;
    __hip_bfloat16* O = Wt + (size_t)mat * DMODEL * DMODEL;
    int tx = threadIdx.x & 31, ty = threadIdx.x >> 5;
#pragma unroll
    for (int i = 0; i < 32; i += 8)
        tile[ty + i][tx] = __float2bfloat16(W[(size_t)(tr * 32 + ty + i) * DMODEL + tc * 32 + tx]);
    __syncthreads();
#pragma unroll
    for (int i = 0; i < 32; i += 8)
        O[(size_t)(tc * 32 + ty + i) * DMODEL + tr * 32 + tx] = tile[tx][ty + i];
}

// ---------------- 2. QKV projection: pipelined MFMA GEMM, XCD-swizzled ----------
// 128x128 tile, BK=32, 4 waves 2x2. Reg prefetch dist 2, LDS dbuf, 1 barrier/step.
// (256,2): ~256 VGPR cap -> prefetch regs stay live; 2 blocks/CU.
__global__ __launch_bounds__(256, 2) void qkv_proj(
    const float* __restrict__ xq,
    const float* __restrict__ xk,
    const float* __restrict__ xv,
    const __hip_bfloat16* __restrict__ Wt,
    const float* __restrict__ bq,
    const float* __restrict__ bk,
    const float* __restrict__ bv,
    __hip_bfloat16* __restrict__ Qr,
    __hip_bfloat16* __restrict__ Kr,
    __hip_bfloat16* __restrict__ Vt)
{
    __shared__ __hip_bfloat16 As[2][128 * 32];
    __shared__ __hip_bfloat16 Bs[2][128 * 32];

    // XCD swizzle: all 6 nt-blocks of one (mat,mt) share bid%8 -> same XCD L2.
    int xcd  = blockIdx.x & 7;
    int s    = blockIdx.x >> 3;
    int nt   = s % 6;
    int pair = (s / 6) * 8 + xcd;
    int mat  = pair >> 6;
    int mt   = pair & 63;
    int m0   = mt * 128, n0 = nt * 128;

    const float* X          = (mat == 0) ? xq : (mat == 1) ? xk : xv;
    const __hip_bfloat16* W = Wt + (size_t)mat * DMODEL * DMODEL;
    const float* bias       = (mat == 0) ? bq : (mat == 1) ? bk : bv;

    int tid  = threadIdx.x;
    int w    = tid >> 6, lane = tid & 63;
    int l16  = lane & 15, quad = lane >> 4;
    int wm   = w >> 1, wn = w & 1;

    // staging map: thread -> (row rS, cols cS..cS+15) of the 128x32 tile
    int rS = tid >> 1;                 // 0..127
    int cS = (tid & 1) << 4;           // 0 or 16
    const float*          xb = X + (size_t)(m0 + rS) * DMODEL + cS;
    const __hip_bfloat16* wb = W + (size_t)(n0 + rS) * DMODEL + cS;
    int ldsOff = rS * 32 + cS;

    float4 fA0, fA1, fA2, fA3;         // prefetched A (fp32, 16 elems)
    uint4  rB0, rB1;                   // prefetched B (bf16, 16 elems)

#define QKV_LOAD(k0_) {                                                        \
        fA0 = *(const float4*)(xb + (k0_));                                    \
        fA1 = *(const float4*)(xb + (k0_) + 4);                                \
        fA2 = *(const float4*)(xb + (k0_) + 8);                                \
        fA3 = *(const float4*)(xb + (k0_) + 12);                               \
        rB0 = *(const uint4*)(wb + (k0_));                                     \
        rB1 = *(const uint4*)(wb + (k0_) + 8); }

#define QKV_STORE(buf_) {                                                      \
        *(bf16x8*)&As[buf_][ldsOff] =                                          \
            (bf16x8){ (__bf16)fA0.x, (__bf16)fA0.y, (__bf16)fA0.z, (__bf16)fA0.w, \
                      (__bf16)fA1.x, (__bf16)fA1.y, (__bf16)fA1.z, (__bf16)fA1.w }; \
        *(bf16x8*)&As[buf_][ldsOff + 8] =                                      \
            (bf16x8){ (__bf16)fA2.x, (__bf16)fA2.y, (__bf16)fA2.z, (__bf16)fA2.w, \
                      (__bf16)fA3.x, (__bf16)fA3.y, (__bf16)fA3.z, (__bf16)fA3.w }; \
        *(uint4*)&Bs[buf_][ldsOff]     = rB0;                                  \
        *(uint4*)&Bs[buf_][ldsOff + 8] = rB1; }

    f32x4 acc[4][4] = {};

    QKV_LOAD(0);
    QKV_STORE(0);
    QKV_LOAD(32);
    __syncthreads();

    for (int it = 0; it < 24; ++it) {
        int buf = it & 1;
        if (it + 1 < 24) QKV_STORE(buf ^ 1);          // tile it+1 (regs) -> other buffer
        if (it + 2 < 24) QKV_LOAD((it + 2) * 32);     // global prefetch, 2 steps ahead

        bf16x8 a[4], b[4];
#pragma unroll
        for (int i = 0; i < 4; ++i)
            a[i] = *(const bf16x8*)&As[buf][(wm * 64 + i * 16 + l16) * 32 + quad * 8];
#pragma unroll
        for (int j = 0; j < 4; ++j)
            b[j] = *(const bf16x8*)&Bs[buf][(wn * 64 + j * 16 + l16) * 32 + quad * 8];
#pragma unroll
        for (int i = 0; i < 4; ++i)
#pragma unroll
            for (int j = 0; j < 4; ++j)
                acc[i][j] = __builtin_amdgcn_mfma_f32_16x16x32_bf16(a[i], b[j], acc[i][j], 0, 0, 0);

        __syncthreads();
    }
#undef QKV_LOAD
#undef QKV_STORE

    // epilogue
#pragma unroll
    for (int j = 0; j < 4; ++j) {
        int col = n0 + wn * 64 + j * 16 + l16;
        float bc = bias[col];
        if (mat == 0) {
#pragma unroll
            for (int i = 0; i < 4; ++i) {
                int row0 = m0 + wm * 64 + i * 16 + quad * 4;
#pragma unroll
                for (int r = 0; r < 4; ++r)
                    Qr[(size_t)(row0 + r) * DMODEL + col] =
                        __float2bfloat16((acc[i][j][r] + bc) * QSCALE);
            }
        } else if (mat == 1) {
#pragma unroll
            for (int i = 0; i < 4; ++i) {
                int row0 = m0 + wm * 64 + i * 16 + quad * 4;
#pragma unroll
                for (int r = 0; r < 4; ++r)
                    Kr[(size_t)(row0 + r) * DMODEL + col] =
                        __float2bfloat16(acc[i][j][r] + bc);
            }
        } else {
            int h = col / 48, dh = col - h * 48;
#pragma unroll
            for (int i = 0; i < 4; ++i) {
                int row0 = m0 + wm * 64 + i * 16 + quad * 4;
                int bb = row0 >> 11, s0 = row0 & 2047;
                ushort4 pk;
                union { __hip_bfloat16 b; unsigned short u; } cv;
                cv.b = __float2bfloat16(acc[i][j][0] + bc); pk.x = cv.u;
                cv.b = __float2bfloat16(acc[i][j][1] + bc); pk.y = cv.u;
                cv.b = __float2bfloat16(acc[i][j][2] + bc); pk.z = cv.u;
                cv.b = __float2bfloat16(acc[i][j][3] + bc); pk.w = cv.u;
                *(ushort4*)(Vt + ((size_t)(bb * NHEAD + h) * DHEAD + dh) * SEQ + s0) = pk;
            }
        }
    }
}

// ---------------- 3. MFMA causal flash attention, operand-swapped ----------------
// (256,3): 3 blocks/CU (= LDS cap), VGPR headroom for deeper scheduling.
__global__ __launch_bounds__(256, 3) void attn(
    const __hip_bfloat16* __restrict__ Qr,
    const __hip_bfloat16* __restrict__ Kr,
    const __hip_bfloat16* __restrict__ Vt,
    __hip_bfloat16* __restrict__ Ao)
{
    __shared__ __hip_bfloat16 Ks[2][64][72];   // cols 48..63 zeroed (DH pad)
    __shared__ __hip_bfloat16 Vs[2][48][72];   // V^T tile [d][kk]
    __shared__ __hip_bfloat16 Ps[4][32][72];   // per-wave P, [q_local][k], A-frag layout

    int tid  = threadIdx.x;
    int w    = tid >> 6, lane = tid & 63;
    int l16  = lane & 15, quad = lane >> 4;
    int bh   = blockIdx.x & 63;
    int qt   = 15 - (blockIdx.x >> 6);         // heavy q-tiles dispatch first
    int q0   = qt * 128;
    int b    = bh >> 4, h = bh & 15;
    size_t rowbase = (size_t)b * SEQ;

    const __hip_bfloat16* Qp = Qr + rowbase * DMODEL + h * DHEAD;
    const __hip_bfloat16* Kp = Kr + rowbase * DMODEL + h * DHEAD;
    const __hip_bfloat16* Vp = Vt + (size_t)bh * DHEAD * SEQ;

    for (int idx = tid; idx < 1024; idx += 256) {
        int buf = idx >> 9, r = (idx >> 3) & 63, c = idx & 7;
        ((unsigned int*)&Ks[buf][r][48])[c] = 0u;
    }

    bf16x8 bQ0[2], bQ1[2];
#pragma unroll
    for (int i = 0; i < 2; ++i) {
        int qrow = q0 + w * 32 + i * 16 + l16;
        bQ0[i] = *(const bf16x8*)(Qp + (size_t)qrow * DMODEL + quad * 8);
        bQ1[i] = (bf16x8){};
        if (quad < 2)
            bQ1[i] = *(const bf16x8*)(Qp + (size_t)qrow * DMODEL + 32 + quad * 8);
    }

    int rK = tid >> 2, oK = (tid & 3) * 12;
    int dV = tid >> 3, oV = (tid & 7) * 8;

    uint2 kr0, kr1, kr2; uint4 vr0, vr1;

#define ATTN_LOAD(kt_) {                                                        \
        int k0_ = (kt_) * 64;                                                   \
        const __hip_bfloat16* kb_ = Kp + (size_t)(k0_ + rK) * DMODEL + oK;      \
        kr0 = *(const uint2*)(kb_);                                             \
        kr1 = *(const uint2*)(kb_ + 4);                                         \
        kr2 = *(const uint2*)(kb_ + 8);                                         \
        vr0 = *(const uint4*)(Vp + (size_t)dV * SEQ + k0_ + oV);                \
        if (tid < 128) vr1 = *(const uint4*)(Vp + (size_t)(32 + dV) * SEQ + k0_ + oV); }

#define ATTN_STORE(buf_) {                                                      \
        __hip_bfloat16* kd_ = &Ks[buf_][rK][oK];                                \
        *(uint2*)(kd_)     = kr0;                                               \
        *(uint2*)(kd_ + 4) = kr1;                                               \
        *(uint2*)(kd_ + 8) = kr2;                                               \
        *(uint4*)&Vs[buf_][dV][oV] = vr0;                                       \
        if (tid < 128) *(uint4*)&Vs[buf_][32 + dV][oV] = vr1; }

    f32x4 O[2][3] = {};
    float lsum[2] = {0.f, 0.f};

    int ktmax = 2 * qt + 1;
    ATTN_LOAD(0);
    ATTN_STORE(0);
    if (ktmax >= 1) ATTN_LOAD(1);
    __syncthreads();

    for (int kt = 0; kt <= ktmax; ++kt) {
        int buf = kt & 1;
        int k0  = kt * 64;
        if (kt + 1 <= ktmax) ATTN_STORE(buf ^ 1);
        if (kt + 2 <= ktmax) ATTN_LOAD(kt + 2);

        bf16x8 aK0[4], aK1[4];
#pragma unroll
        for (int t = 0; t < 4; ++t) {
            aK0[t] = *(const bf16x8*)&Ks[buf][16 * t + l16][quad * 8];
            aK1[t] = *(const bf16x8*)&Ks[buf][16 * t + l16][32 + quad * 8];
        }

#pragma unroll
        for (int i = 0; i < 2; ++i) {
            int qbase = q0 + w * 32 + i * 16;
            if (k0 > qbase + 15) continue;

            f32x4 s[4];
#pragma unroll
            for (int t = 0; t < 4; ++t) {
                f32x4 z = {};
                z    = __builtin_amdgcn_mfma_f32_16x16x32_bf16(aK0[t], bQ0[i], z, 0, 0, 0);
                s[t] = __builtin_amdgcn_mfma_f32_16x16x32_bf16(aK1[t], bQ1[i], z, 0, 0, 0);
            }

            if (k0 + 63 > qbase) {
                int qg = qbase + l16;
#pragma unroll
                for (int t = 0; t < 4; ++t) {
                    int kg = k0 + 16 * t + quad * 4;
#pragma unroll
                    for (int r = 0; r < 4; ++r)
                        if (kg + r > qg) s[t][r] = -1e30f;
                }
            }

            float ls = 0.f;
#pragma unroll
            for (int t = 0; t < 4; ++t) {
                float p0 = exp2f(s[t][0]), p1 = exp2f(s[t][1]);
                float p2 = exp2f(s[t][2]), p3 = exp2f(s[t][3]);
                ls += (p0 + p1) + (p2 + p3);
                union { __bf16 hv[4]; uint2 u2; } pk;
                pk.hv[0] = (__bf16)p0; pk.hv[1] = (__bf16)p1;
                pk.hv[2] = (__bf16)p2; pk.hv[3] = (__bf16)p3;
                *(uint2*)&Ps[w][i * 16 + l16][16 * t + quad * 4] = pk.u2;
            }
            lsum[i] += ls;
        }

        bf16x8 bV0[3], bV1[3];
#pragma unroll
        for (int dt = 0; dt < 3; ++dt) {
            bV0[dt] = *(const bf16x8*)&Vs[buf][dt * 16 + l16][quad * 8];
            bV1[dt] = *(const bf16x8*)&Vs[buf][dt * 16 + l16][32 + quad * 8];
        }

#pragma unroll
        for (int i = 0; i < 2; ++i) {
            int qbase = q0 + w * 32 + i * 16;
            if (k0 > qbase + 15) continue;
            bf16x8 aP0 = *(const bf16x8*)&Ps[w][i * 16 + l16][quad * 8];
            bf16x8 aP1 = *(const bf16x8*)&Ps[w][i * 16 + l16][32 + quad * 8];
#pragma unroll
            for (int dt = 0; dt < 3; ++dt) {
                O[i][dt] = __builtin_amdgcn_mfma_f32_16x16x32_bf16(aP0, bV0[dt], O[i][dt], 0, 0, 0);
                O[i][dt] = __builtin_amdgcn_mfma_f32_16x16x32_bf16(aP1, bV1[dt], O[i][dt], 0, 0, 0);
            }
        }

        __syncthreads();
    }

#pragma unroll
    for (int i = 0; i < 2; ++i) {
        lsum[i] += __shfl_xor(lsum[i], 16, 64);
        lsum[i] += __shfl_xor(lsum[i], 32, 64);
    }

#pragma unroll
    for (int i = 0; i < 2; ++i) {
#pragma unroll
        for (int r = 0; r < 4; ++r) {
            float linv = 1.f / __shfl(lsum[i], quad * 4 + r, 64);
            size_t g = (rowbase + q0 + w * 32 + i * 16 + quad * 4 + r) * DMODEL + h * DHEAD + l16;
            Ao[g + 0]  = __float2bfloat16(O[i][0][r] * linv);
            Ao[g + 16] = __float2bfloat16(O[i][1][r] * linv);
            Ao[g + 32] = __float2bfloat16(O[i][2][r] * linv);
        }
    }
#undef ATTN_LOAD
#undef ATTN_STORE
}

// ---------------- 4. LayerNorm (eps = 1e-3), vectorized, fp32 out ----------------
__global__ __launch_bounds__(192) void lnorm(
    const __hip_bfloat16* __restrict__ Ao,
    const float* __restrict__ gamma,
    const float* __restrict__ beta,
    float* __restrict__ out)
{
    __shared__ float rs_[3], rq_[3];
    int row = blockIdx.x;
    int t   = threadIdx.x;
    size_t base = (size_t)row * DMODEL + t * 4;

    ushort4 u = *(const ushort4*)(Ao + base);
    float x0, x1, x2, x3;
    { unsigned int v = (unsigned int)u.x << 16; __builtin_memcpy(&x0, &v, 4); }
    { unsigned int v = (unsigned int)u.y << 16; __builtin_memcpy(&x1, &v, 4); }
    { unsigned int v = (unsigned int)u.z << 16; __builtin_memcpy(&x2, &v, 4); }
    { unsigned int v = (unsigned int)u.w << 16; __builtin_memcpy(&x3, &v, 4); }

    float s = x0 + x1 + x2 + x3;
    float q = x0 * x0 + x1 * x1 + x2 * x2 + x3 * x3;
#pragma unroll
    for (int m = 32; m >= 1; m >>= 1) {
        s += __shfl_xor(s, m, 64);
        q += __shfl_xor(q, m, 64);
    }
    int wv = t >> 6;
    if ((t & 63) == 0) { rs_[wv] = s; rq_[wv] = q; }
    __syncthreads();
    float ts = rs_[0] + rs_[1] + rs_[2];
    float tq = rq_[0] + rq_[1] + rq_[2];
    float mu  = ts * (1.f / 768.f);
    float var = tq * (1.f / 768.f) - mu * mu;
    float rstd = rsqrtf(var + 1e-3f);

    float4 g  = *(const float4*)(gamma + t * 4);
    float4 be = *(const float4*)(beta + t * 4);
    float4 o;
    o.x = (x0 - mu) * rstd * g.x + be.x;
    o.y = (x1 - mu) * rstd * g.y + be.y;
    o.z = (x2 - mu) * rstd * g.z + be.z;
    o.w = (x3 - mu) * rstd * g.w + be.w;
    *(float4*)(out + base) = o;
}

extern "C" void kernel_launch(void* const* d_in, const int* in_sizes, int n_in,
                              void* d_out, int out_size, void* d_ws, size_t ws_size,
                              hipStream_t stream) {
    const float* q     = (const float*)d_in[0];
    const float* k     = (const float*)d_in[1];
    const float* v     = (const float*)d_in[2];
    const float* Wq    = (const float*)d_in[3];
    const float* bq    = (const float*)d_in[4];
    const float* Wk    = (const float*)d_in[5];
    const float* bk    = (const float*)d_in[6];
    const float* Wv    = (const float*)d_in[7];
    const float* bv    = (const float*)d_in[8];
    const float* gamma = (const float*)d_in[9];
    const float* beta  = (const float*)d_in[10];

    char* basep = (char*)d_ws;
    __hip_bfloat16* Wt = (__hip_bfloat16*)basep;
    __hip_bfloat16* Qr = (__hip_bfloat16*)(basep + 3538944);
    __hip_bfloat16* Kr = Qr + (size_t)NROWS * DMODEL;
    __hip_bfloat16* Vt = Kr + (size_t)NROWS * DMODEL;
    __hip_bfloat16* Ao = Vt + (size_t)NROWS * DMODEL;
    float* out = (float*)d_out;

    hipLaunchKernelGGL(transpose_w, dim3(1728), dim3(256), 0, stream, Wq, Wk, Wv, Wt);
    hipLaunchKernelGGL(qkv_proj, dim3(1152), dim3(256), 0, stream,
                       q, k, v, Wt, bq, bk, bv, Qr, Kr, Vt);
    hipLaunchKernelGGL(attn, dim3(1024), dim3(256), 0, stream, Qr, Kr, Vt, Ao);
    hipLaunchKernelGGL(lnorm, dim3(8192), dim3(192), 0, stream, Ao, gamma, beta, out);
}